// Round 4
// baseline (176.970 us; speedup 1.0000x reference)
//
#include <hip/hip_runtime.h>

// Lee oscillator, 49 iters, element-wise in x.
//   u' = tanh(0.6u - 0.6v - 0.5z + 0.5x)
//   v' = tanh(0.6u + 0.6v - 0.5z + 0.5x)
//   z' = (v'-u')*exp(-50 x^2) + tanh(x)
//
// Key algebra: output z49 = (v49-u49)*decay + tanh(x), |v-u| <= 2.
// If decay = exp(-50x^2) <= 1e-4 (x^2 > 0.1842), z49 = tanh(x) +/- 2e-4
// -> no iteration needed. ~67% of N(0,1) elements take this path.
// 3-kernel pipeline: zero counter -> classify+compact slow indices (+write
// tanh(x) everywhere) -> 49-iter loop only on the compacted ~33%.
//
// Slow-path inner loop in r-space with merged reciprocal:
//   e=exp(2y), tanh(y)=1-2/(e+1); A=eu+1,B=ev+1, RP=rcp(A*B),
//   u'=fma(B,-2RP,1), v'=fma(A,-2RP,1), z'=fma((B-A)*RP, 2*decay, w).
// 13 VALU + 2 v_exp + 1 v_rcp per element-iter. (Note: v_pk fp32 is
// throughput-neutral on gfx950 - 157 TF counts scalar fma - so no packing.)

#define NITER 49
#define X2_THR 0.1842068f   // decay >= 1e-4 boundary

__device__ __forceinline__ float exp2f_hw(float a) { return __builtin_amdgcn_exp2f(a); }
__device__ __forceinline__ float rcpf_hw(float a) { return __builtin_amdgcn_rcpf(a); }

// Newton-refined tanh: ~1 ulp (accuracy anchor for w = tanh(x))
__device__ __forceinline__ float tanh_acc(float x) {
    const float T = 2.885390081777927f;  // 2*log2(e)
    float e = exp2f_hw(T * x);
    float d = e + 1.0f;
    float r = rcpf_hw(d);
    r = r * __builtin_fmaf(-d, r, 2.0f);
    return __builtin_fmaf(-2.0f, r, 1.0f);
}

__global__ void lee_zero_ctr(unsigned* __restrict__ ctr) {
    if (threadIdx.x == 0) ctr[0] = 0;
}

// k1: out[i] = tanh(x[i]) for all; compact indices with x^2 <= X2_THR.
__global__ __launch_bounds__(256) void lee_classify(const float* __restrict__ x,
                                                    float* __restrict__ out,
                                                    unsigned* __restrict__ ctr,
                                                    unsigned* __restrict__ list,
                                                    int n4) {
    int i = blockIdx.x * blockDim.x + threadIdx.x;
    if (i >= n4) return;
    float4 xv = reinterpret_cast<const float4*>(x)[i];
    float xs[4] = {xv.x, xv.y, xv.z, xv.w};
    float os[4];
    unsigned slowmask = 0, c = 0;
#pragma unroll
    for (int j = 0; j < 4; ++j) {
        float xx = xs[j];
        os[j] = tanh_acc(xx);
        unsigned slow = (xx * xx <= X2_THR) ? 1u : 0u;
        slowmask |= slow << j;
        c += slow;
    }
    float4 ov; ov.x = os[0]; ov.y = os[1]; ov.z = os[2]; ov.w = os[3];
    reinterpret_cast<float4*>(out)[i] = ov;

    // wave-level exclusive scan of per-thread slow count, one atomic per wave
    unsigned lane = threadIdx.x & 63u;
    unsigned incl = c;
#pragma unroll
    for (int off = 1; off < 64; off <<= 1) {
        unsigned t = __shfl_up(incl, off, 64);
        if (lane >= (unsigned)off) incl += t;
    }
    unsigned total = __shfl(incl, 63, 64);
    unsigned base = 0;
    if (lane == 63) base = atomicAdd(ctr, total);
    base = __shfl(base, 63, 64);
    unsigned pos = base + incl - c;
#pragma unroll
    for (int j = 0; j < 4; ++j) {
        if (slowmask & (1u << j)) list[pos++] = (unsigned)(i * 4 + j);
    }
}

// k2: full 49-iter recurrence on listed elements only (all lanes productive).
__global__ __launch_bounds__(256) void lee_slow(const float* __restrict__ x,
                                                float* __restrict__ out,
                                                const unsigned* __restrict__ ctr,
                                                const unsigned* __restrict__ list) {
    unsigned j = blockIdx.x * blockDim.x + threadIdx.x;
    if (j >= ctr[0]) return;
    unsigned idx = list[j];
    float xx = x[idx];

    const float T   = 2.885390081777927f;
    const float C05 = 0.5f * T;
    const float C06 = 0.6f * T;
    const float NK  = -72.13475204444817f;  // -50*log2(e)

    float pxT = C05 * xx;
    float d2  = 2.0f * exp2f_hw(NK * xx * xx);  // 2*exp(-50 x^2)
    float w   = tanh_acc(xx);
    float u = 0.2f, v = 0.0f, z = 0.2f;

#pragma unroll 7
    for (int it = 0; it < NITER; ++it) {
        float cT  = __builtin_fmaf(-C05, z, pxT);
        float sT  = __builtin_fmaf(C06, u, cT);
        float auT = __builtin_fmaf(-C06, v, sT);
        float avT = __builtin_fmaf(C06, v, sT);
        float EU  = exp2f_hw(auT);
        float EV  = exp2f_hw(avT);
        float A   = EU + 1.0f;
        float B   = EV + 1.0f;
        float RP  = rcpf_hw(A * B);
        float R2  = -2.0f * RP;
        u = __builtin_fmaf(B, R2, 1.0f);
        v = __builtin_fmaf(A, R2, 1.0f);
        z = __builtin_fmaf((B - A) * RP, d2, w);
    }
    out[idx] = z;
}

// Fallback monolithic kernel (round-3) if ws_size is insufficient.
typedef float v2f __attribute__((ext_vector_type(2)));
__global__ __launch_bounds__(256, 8) void lee_mono(const float* __restrict__ x,
                                                   float* __restrict__ out,
                                                   int n4) {
    int i = blockIdx.x * blockDim.x + threadIdx.x;
    if (i >= n4) return;
    const float T   = 2.885390081777927f;
    const float C05 = 0.5f * T;
    const float C06 = 0.6f * T;
    const float NK  = -72.13475204444817f;
    float4 xv = reinterpret_cast<const float4*>(x)[i];
    float xs[4] = {xv.x, xv.y, xv.z, xv.w};
    float pxT[4], d2[4], w[4], u[4], v[4], z[4];
#pragma unroll
    for (int j = 0; j < 4; ++j) {
        float xx = xs[j];
        pxT[j] = C05 * xx;
        d2[j]  = 2.0f * exp2f_hw(NK * xx * xx);
        w[j]   = tanh_acc(xx);
        u[j] = 0.2f; v[j] = 0.0f; z[j] = 0.2f;
    }
    for (int it = 0; it < NITER; ++it) {
#pragma unroll
        for (int j = 0; j < 4; ++j) {
            float cT  = __builtin_fmaf(-C05, z[j], pxT[j]);
            float sT  = __builtin_fmaf(C06, u[j], cT);
            float auT = __builtin_fmaf(-C06, v[j], sT);
            float avT = __builtin_fmaf(C06, v[j], sT);
            float EU  = exp2f_hw(auT);
            float EV  = exp2f_hw(avT);
            float A   = EU + 1.0f;
            float B   = EV + 1.0f;
            float RP  = rcpf_hw(A * B);
            float R2  = -2.0f * RP;
            u[j] = __builtin_fmaf(B, R2, 1.0f);
            v[j] = __builtin_fmaf(A, R2, 1.0f);
            z[j] = __builtin_fmaf((B - A) * RP, d2[j], w[j]);
        }
    }
    float4 ov; ov.x = z[0]; ov.y = z[1]; ov.z = z[2]; ov.w = z[3];
    reinterpret_cast<float4*>(out)[i] = ov;
}

extern "C" void kernel_launch(void* const* d_in, const int* in_sizes, int n_in,
                              void* d_out, int out_size, void* d_ws, size_t ws_size,
                              hipStream_t stream) {
    const float* x = (const float*)d_in[0];
    float* out = (float*)d_out;
    int n = in_sizes[0];        // 2097152
    int n4 = n / 4;
    size_t need = 64 + (size_t)n * sizeof(unsigned);
    if ((n % 4) == 0 && ws_size >= need) {
        unsigned* ctr  = (unsigned*)d_ws;
        unsigned* list = (unsigned*)((char*)d_ws + 64);
        lee_zero_ctr<<<1, 64, 0, stream>>>(ctr);
        lee_classify<<<(n4 + 255) / 256, 256, 0, stream>>>(x, out, ctr, list, n4);
        lee_slow<<<(n + 255) / 256, 256, 0, stream>>>(x, out, ctr, list);
    } else {
        lee_mono<<<(n4 + 255) / 256, 256, 0, stream>>>(x, out, n4);
    }
}

// Round 5
// 84.073 us; speedup vs baseline: 2.1050x; 2.1050x over previous
//
#include <hip/hip_runtime.h>

// Lee oscillator, 49 iters, element-wise in x.
//   u' = tanh(0.6u - 0.6v - 0.5z + 0.5x)
//   v' = tanh(0.6u + 0.6v - 0.5z + 0.5x)
//   z' = (v'-u')*exp(-50 x^2) + tanh(x)
//
// Output algebra: z49 = (v49-u49)*decay + tanh(x), |v-u| < 2.
// decay = exp(-50x^2) <= 1e-4  (x^2 > 0.1842, ~67% of N(0,1) inputs)
//   ==> z49 = tanh(x) +/- 2e-4: no iteration needed.
//
// FUSED single kernel (round-4 lesson: a single global atomic counter
// serialized the device -> 97us at 1.5% VALUBusy; compaction must be
// block-local): each 256-thread block owns 1024 contiguous elements;
// slow elements are packed into LDS via a block-local LDS atomic, then
// consumed by all threads stride-256 (no lane divergence in the 49-iter
// loop; empty waves exit and free the SIMD).
//
// Slow loop in r-space, merged reciprocal:
//   e=exp(2y), tanh(y)=1-2/(e+1); A=eu+1, B=ev+1, RP=rcp(A*B),
//   u'=fma(B,-2RP,1), v'=fma(A,-2RP,1), z'=fma((B-A)*RP, 2*decay, w).
// 13 VALU + 2 v_exp + 1 v_rcp per element-iter.

#define NITER 49
#define X2_THR 0.1842068f   // decay >= 1e-4 boundary

__device__ __forceinline__ float exp2f_hw(float a) { return __builtin_amdgcn_exp2f(a); }
__device__ __forceinline__ float rcpf_hw(float a) { return __builtin_amdgcn_rcpf(a); }

// Newton-refined tanh, ~1 ulp (per-step error is chaotically amplified ~4e4x;
// keep it at fp32 rounding scale).
__device__ __forceinline__ float tanh_acc(float x) {
    const float T = 2.885390081777927f;  // 2*log2(e)
    float e = exp2f_hw(T * x);
    float d = e + 1.0f;
    float r = rcpf_hw(d);
    r = r * __builtin_fmaf(-d, r, 2.0f);
    return __builtin_fmaf(-2.0f, r, 1.0f);
}

__device__ __forceinline__ float lee_iterate(float xx) {
    const float T   = 2.885390081777927f;
    const float C05 = 0.5f * T;
    const float C06 = 0.6f * T;
    const float NK  = -72.13475204444817f;   // -50*log2(e)
    float pxT = C05 * xx;
    float d2  = 2.0f * exp2f_hw(NK * xx * xx);  // 2*exp(-50 x^2)
    float w   = tanh_acc(xx);
    float u = 0.2f, v = 0.0f, z = 0.2f;
#pragma unroll 7
    for (int it = 0; it < NITER; ++it) {
        float cT  = __builtin_fmaf(-C05, z, pxT);
        float sT  = __builtin_fmaf(C06, u, cT);
        float auT = __builtin_fmaf(-C06, v, sT);
        float avT = __builtin_fmaf(C06, v, sT);
        float EU  = exp2f_hw(auT);
        float EV  = exp2f_hw(avT);
        float A   = EU + 1.0f;
        float B   = EV + 1.0f;
        float RP  = rcpf_hw(A * B);
        float R2  = -2.0f * RP;
        u = __builtin_fmaf(B, R2, 1.0f);
        v = __builtin_fmaf(A, R2, 1.0f);
        z = __builtin_fmaf((B - A) * RP, d2, w);
    }
    return z;
}

__global__ __launch_bounds__(256) void lee_fused(const float* __restrict__ x,
                                                 float* __restrict__ out,
                                                 int n4) {
    __shared__ float s_x[1024];
    __shared__ unsigned short s_idx[1024];
    __shared__ unsigned s_cnt;

    int tid = threadIdx.x;
    int i = blockIdx.x * 256 + tid;   // float4 index
    if (tid == 0) s_cnt = 0;
    __syncthreads();

    if (i < n4) {
        float4 xv = reinterpret_cast<const float4*>(x)[i];
        float xs[4] = {xv.x, xv.y, xv.z, xv.w};
        float os[4];
        unsigned slowmask = 0, c = 0;
#pragma unroll
        for (int j = 0; j < 4; ++j) {
            float xx = xs[j];
            os[j] = tanh_acc(xx);                 // fast-path result
            unsigned slow = (xx * xx <= X2_THR) ? 1u : 0u;
            slowmask |= slow << j;
            c += slow;
        }
        float4 ov; ov.x = os[0]; ov.y = os[1]; ov.z = os[2]; ov.w = os[3];
        reinterpret_cast<float4*>(out)[i] = ov;

        if (c) {
            unsigned pos = atomicAdd(&s_cnt, c);  // block-local, low contention
#pragma unroll
            for (int j = 0; j < 4; ++j) {
                if (slowmask & (1u << j)) {
                    s_x[pos] = xs[j];
                    s_idx[pos] = (unsigned short)(tid * 4 + j);
                    ++pos;
                }
            }
        }
    }
    __syncthreads();

    unsigned cnt = s_cnt;
    long long base = (long long)blockIdx.x * 1024;
    for (unsigned s = tid; s < cnt; s += 256) {
        float z = lee_iterate(s_x[s]);
        out[base + s_idx[s]] = z;
    }
}

// Fallback monolithic kernel for sizes not divisible by 4.
__global__ __launch_bounds__(256) void lee_mono(const float* __restrict__ x,
                                                float* __restrict__ out, int n) {
    int i = blockIdx.x * blockDim.x + threadIdx.x;
    if (i >= n) return;
    float xx = x[i];
    out[i] = (xx * xx <= X2_THR) ? lee_iterate(xx) : tanh_acc(xx);
}

extern "C" void kernel_launch(void* const* d_in, const int* in_sizes, int n_in,
                              void* d_out, int out_size, void* d_ws, size_t ws_size,
                              hipStream_t stream) {
    const float* x = (const float*)d_in[0];
    float* out = (float*)d_out;
    int n = in_sizes[0];     // 2097152
    if ((n & 3) == 0) {
        int n4 = n / 4;
        int grid = (n4 + 255) / 256;
        lee_fused<<<grid, 256, 0, stream>>>(x, out, n4);
    } else {
        lee_mono<<<(n + 255) / 256, 256, 0, stream>>>(x, out, n);
    }
}

// Round 6
// 79.863 us; speedup vs baseline: 2.2159x; 1.0527x over previous
//
#include <hip/hip_runtime.h>

// Lee oscillator, 49 iters, element-wise in x.
//   u' = tanh(0.6u - 0.6v - 0.5z + 0.5x)
//   v' = tanh(0.6u + 0.6v - 0.5z + 0.5x)
//   z' = (v'-u')*exp(-50 x^2) + tanh(x)
//
// z49 = (v49-u49)*decay + tanh(x), |v-u| < 2. decay = exp(-50x^2) <= 2e-3
// (x^2 > 0.124292) => z49 = tanh(x) +/- 4e-3 (threshold 2e-2): fast path,
// ~72% of N(0,1) inputs.
//
// Round-5 lesson: block-level compaction left a 2x structural gap (one
// residency batch, barrier drain, 67% round fill). This version is
// WAVE-AUTONOMOUS: each wave owns 384 contiguous elems, compacts slow ones
// (cnt ~ 106 +/- 9) into its own LDS segment with ballot-prefix (no atomic,
// no __syncthreads), then runs ONE 49-iter round at 2 elems/lane (ILP2,
// 83% fill, deterministic). Fast elems: exec-masked tanh stores; slow elems
// written only by the slow path (no store-ordering hazard).
//
// Slow loop in r-space, merged reciprocal:
//   e=exp(2y), tanh(y)=1-2/(e+1); A=eu+1, B=ev+1, RP=rcp(A*B),
//   u'=fma(B,-2RP,1), v'=fma(A,-2RP,1), z'=fma((B-A)*RP, 2*decay, w).
// 13 VALU + 2 v_exp + 1 v_rcp per element-iter (3 trans/iter is minimal).

#define NITER 49
#define X2_THR 0.1242922f   // ln(500)/50: decay <= 2e-3
#define WAVE_ELEMS 384      // 64 float4 + 64 float2 per wave
#define WAVES_PER_BLOCK 2

typedef unsigned long long u64;

__device__ __forceinline__ float exp2f_hw(float a) { return __builtin_amdgcn_exp2f(a); }
__device__ __forceinline__ float rcpf_hw(float a) { return __builtin_amdgcn_rcpf(a); }

// Newton-refined tanh, ~1 ulp.
__device__ __forceinline__ float tanh_acc(float x) {
    const float T = 2.885390081777927f;  // 2*log2(e)
    float e = exp2f_hw(T * x);
    float d = e + 1.0f;
    float r = rcpf_hw(d);
    r = r * __builtin_fmaf(-d, r, 2.0f);
    return __builtin_fmaf(-2.0f, r, 1.0f);
}

__global__ __launch_bounds__(128) void lee_wave(const float* __restrict__ x,
                                                float* __restrict__ out,
                                                long long n) {
    __shared__ float s_x[WAVES_PER_BLOCK][WAVE_ELEMS];
    __shared__ unsigned short s_idx[WAVES_PER_BLOCK][WAVE_ELEMS];

    const int wid  = threadIdx.x >> 6;
    const int lane = threadIdx.x & 63;
    const long long w  = (long long)blockIdx.x * WAVES_PER_BLOCK + wid;
    const long long e0 = w * WAVE_ELEMS;
    if (e0 >= n) return;

    const u64 lt = (1ull << lane) - 1ull;

    // ---- load 6 elements/lane: float4 at e0+4*lane, float2 at e0+256+2*lane
    float xs[6];
    bool valid[6];
    const long long ef4 = e0 + 4 * (long long)lane;
    const long long ef2 = e0 + 256 + 2 * (long long)lane;
    if (ef4 + 3 < n) {
        float4 xv = *reinterpret_cast<const float4*>(x + ef4);
        xs[0] = xv.x; xs[1] = xv.y; xs[2] = xv.z; xs[3] = xv.w;
        valid[0] = valid[1] = valid[2] = valid[3] = true;
    } else {
#pragma unroll
        for (int j = 0; j < 4; ++j) {
            valid[j] = (ef4 + j) < n;
            xs[j] = valid[j] ? x[ef4 + j] : 10.0f;
        }
    }
    if (ef2 + 1 < n) {
        float2 xv = *reinterpret_cast<const float2*>(x + ef2);
        xs[4] = xv.x; xs[5] = xv.y;
        valid[4] = valid[5] = true;
    } else {
#pragma unroll
        for (int j = 0; j < 2; ++j) {
            valid[4 + j] = (ef2 + j) < n;
            xs[4 + j] = valid[4 + j] ? x[ef2 + j] : 10.0f;
        }
    }

    // ---- classify + ballot-prefix compact (wave-local, no atomics) + fast stores
    unsigned cnt = 0;
#pragma unroll
    for (int j = 0; j < 6; ++j) {
        float xx = xs[j];
        bool slow = valid[j] && (xx * xx <= X2_THR);
        u64 m = __ballot(slow);
        if (slow) {
            unsigned pos = cnt + (unsigned)__popcll(m & lt);
            int li = (j < 4) ? (4 * lane + j) : (256 + 2 * lane + (j - 4));
            s_x[wid][pos] = xx;
            s_idx[wid][pos] = (unsigned short)li;
        } else if (valid[j]) {
            long long e = (j < 4) ? (ef4 + j) : (ef2 + (j - 4));
            out[e] = tanh_acc(xx);   // fast path: z49 = tanh(x) +/- 4e-3
        }
        cnt += (unsigned)__popcll(m);
    }

    // ---- slow path: 2 elems/lane per round; cnt<=128 with P~0.995 -> 1 round
    const float T   = 2.885390081777927f;
    const float C05 = 0.5f * T;
    const float C06 = 0.6f * T;
    const float NK  = -72.13475204444817f;   // -50*log2(e)

    for (unsigned base = 0; base < cnt; base += 128) {
        unsigned r0 = base + lane, r1 = base + lane + 64;
        bool v0 = r0 < cnt, v1 = r1 < cnt;
        float X[2];
        X[0] = v0 ? s_x[wid][r0] : 10.0f;   // dummy: decay=0, finite everywhere
        X[1] = v1 ? s_x[wid][r1] : 10.0f;

        float pxT[2], d2[2], wv[2], U[2], V[2], Z[2];
#pragma unroll
        for (int k = 0; k < 2; ++k) {
            pxT[k] = C05 * X[k];
            d2[k]  = 2.0f * exp2f_hw(NK * X[k] * X[k]);
            wv[k]  = tanh_acc(X[k]);
            U[k] = 0.2f; V[k] = 0.0f; Z[k] = 0.2f;
        }
#pragma unroll 7
        for (int it = 0; it < NITER; ++it) {
#pragma unroll
            for (int k = 0; k < 2; ++k) {
                float cT  = __builtin_fmaf(-C05, Z[k], pxT[k]);
                float sT  = __builtin_fmaf(C06, U[k], cT);
                float auT = __builtin_fmaf(-C06, V[k], sT);
                float avT = __builtin_fmaf(C06, V[k], sT);
                float EU  = exp2f_hw(auT);
                float EV  = exp2f_hw(avT);
                float A   = EU + 1.0f;
                float B   = EV + 1.0f;
                float RP  = rcpf_hw(A * B);
                float R2  = -2.0f * RP;
                U[k] = __builtin_fmaf(B, R2, 1.0f);
                V[k] = __builtin_fmaf(A, R2, 1.0f);
                Z[k] = __builtin_fmaf((B - A) * RP, d2[k], wv[k]);
            }
        }
        if (v0) out[e0 + s_idx[wid][r0]] = Z[0];
        if (v1) out[e0 + s_idx[wid][r1]] = Z[1];
    }
}

extern "C" void kernel_launch(void* const* d_in, const int* in_sizes, int n_in,
                              void* d_out, int out_size, void* d_ws, size_t ws_size,
                              hipStream_t stream) {
    const float* x = (const float*)d_in[0];
    float* out = (float*)d_out;
    long long n = in_sizes[0];    // 2097152
    long long waves  = (n + WAVE_ELEMS - 1) / WAVE_ELEMS;
    long long blocks = (waves + WAVES_PER_BLOCK - 1) / WAVES_PER_BLOCK;
    lee_wave<<<(int)blocks, 64 * WAVES_PER_BLOCK, 0, stream>>>(x, out, n);
}

// Round 7
// 79.128 us; speedup vs baseline: 2.2365x; 1.0093x over previous
//
#include <hip/hip_runtime.h>

// DIAGNOSTIC ROUND: identical numerics/output to round 6, but the slow phase
// runs 3x (1 real + 2 decoy reps on ~1-ulp-perturbed inputs; decoy stores are
// guarded by a never-true, compiler-unprovable predicate). Purpose: push the
// dispatch above the harness's 43us fill kernels so it appears in rocprof
// top-5 with VALUBusy/Occupancy counters, and measure slow-phase cost as
// S = (bench_diag - bench_r6)/2.
//
// Lee oscillator, 49 iters:
//   u' = tanh(0.6u - 0.6v - 0.5z + 0.5x)
//   v' = tanh(0.6u + 0.6v - 0.5z + 0.5x)
//   z' = (v'-u')*exp(-50 x^2) + tanh(x)
// Fast path (decay <= 2e-3, ~72% of N(0,1)): z49 = tanh(x) +/- 4e-3.
// Wave-autonomous: 384 elems/wave, ballot-prefix compact to LDS, one ILP2
// 49-iter round on the ~106 slow elems.

#define NITER 49
#define X2_THR 0.1242922f   // ln(500)/50: decay <= 2e-3
#define WAVE_ELEMS 384
#define WAVES_PER_BLOCK 2
#define DIAG_REPS 3         // 1 real + 2 decoys (diagnostic)

typedef unsigned long long u64;

__device__ __forceinline__ float exp2f_hw(float a) { return __builtin_amdgcn_exp2f(a); }
__device__ __forceinline__ float rcpf_hw(float a) { return __builtin_amdgcn_rcpf(a); }

__device__ __forceinline__ float tanh_acc(float x) {
    const float T = 2.885390081777927f;  // 2*log2(e)
    float e = exp2f_hw(T * x);
    float d = e + 1.0f;
    float r = rcpf_hw(d);
    r = r * __builtin_fmaf(-d, r, 2.0f);
    return __builtin_fmaf(-2.0f, r, 1.0f);
}

__global__ __launch_bounds__(128) void lee_wave(const float* __restrict__ x,
                                                float* __restrict__ out,
                                                long long n) {
    __shared__ float s_x[WAVES_PER_BLOCK][WAVE_ELEMS];
    __shared__ unsigned short s_idx[WAVES_PER_BLOCK][WAVE_ELEMS];

    const int wid  = threadIdx.x >> 6;
    const int lane = threadIdx.x & 63;
    const long long w  = (long long)blockIdx.x * WAVES_PER_BLOCK + wid;
    const long long e0 = w * WAVE_ELEMS;
    if (e0 >= n) return;

    const u64 lt = (1ull << lane) - 1ull;

    float xs[6];
    bool valid[6];
    const long long ef4 = e0 + 4 * (long long)lane;
    const long long ef2 = e0 + 256 + 2 * (long long)lane;
    if (ef4 + 3 < n) {
        float4 xv = *reinterpret_cast<const float4*>(x + ef4);
        xs[0] = xv.x; xs[1] = xv.y; xs[2] = xv.z; xs[3] = xv.w;
        valid[0] = valid[1] = valid[2] = valid[3] = true;
    } else {
#pragma unroll
        for (int j = 0; j < 4; ++j) {
            valid[j] = (ef4 + j) < n;
            xs[j] = valid[j] ? x[ef4 + j] : 10.0f;
        }
    }
    if (ef2 + 1 < n) {
        float2 xv = *reinterpret_cast<const float2*>(x + ef2);
        xs[4] = xv.x; xs[5] = xv.y;
        valid[4] = valid[5] = true;
    } else {
#pragma unroll
        for (int j = 0; j < 2; ++j) {
            valid[4 + j] = (ef2 + j) < n;
            xs[4 + j] = valid[4 + j] ? x[ef2 + j] : 10.0f;
        }
    }

    unsigned cnt = 0;
#pragma unroll
    for (int j = 0; j < 6; ++j) {
        float xx = xs[j];
        bool slow = valid[j] && (xx * xx <= X2_THR);
        u64 m = __ballot(slow);
        if (slow) {
            unsigned pos = cnt + (unsigned)__popcll(m & lt);
            int li = (j < 4) ? (4 * lane + j) : (256 + 2 * lane + (j - 4));
            s_x[wid][pos] = xx;
            s_idx[wid][pos] = (unsigned short)li;
        } else if (valid[j]) {
            long long e = (j < 4) ? (ef4 + j) : (ef2 + (j - 4));
            out[e] = tanh_acc(xx);
        }
        cnt += (unsigned)__popcll(m);
    }

    const float T   = 2.885390081777927f;
    const float C05 = 0.5f * T;
    const float C06 = 0.6f * T;
    const float NK  = -72.13475204444817f;

#pragma unroll
    for (int rep = 0; rep < DIAG_REPS; ++rep) {
        // rep 0: exact (scale folds to 1.0f). rep>0: ~1-ulp perturbation so
        // the decoy bodies are not CSE-merged with the real one.
        const float scale = 1.0f + (float)rep * 2.4e-7f;
        for (unsigned base = 0; base < cnt; base += 128) {
            unsigned r0 = base + lane, r1 = base + lane + 64;
            bool v0 = r0 < cnt, v1 = r1 < cnt;
            float X[2];
            X[0] = (v0 ? s_x[wid][r0] : 10.0f) * scale;
            X[1] = (v1 ? s_x[wid][r1] : 10.0f) * scale;

            float pxT[2], d2[2], wv[2], U[2], V[2], Z[2];
#pragma unroll
            for (int k = 0; k < 2; ++k) {
                pxT[k] = C05 * X[k];
                d2[k]  = 2.0f * exp2f_hw(NK * X[k] * X[k]);
                wv[k]  = tanh_acc(X[k]);
                U[k] = 0.2f; V[k] = 0.0f; Z[k] = 0.2f;
            }
#pragma unroll 7
            for (int it = 0; it < NITER; ++it) {
#pragma unroll
                for (int k = 0; k < 2; ++k) {
                    float cT  = __builtin_fmaf(-C05, Z[k], pxT[k]);
                    float sT  = __builtin_fmaf(C06, U[k], cT);
                    float auT = __builtin_fmaf(-C06, V[k], sT);
                    float avT = __builtin_fmaf(C06, V[k], sT);
                    float EU  = exp2f_hw(auT);
                    float EV  = exp2f_hw(avT);
                    float A   = EU + 1.0f;
                    float B   = EV + 1.0f;
                    float RP  = rcpf_hw(A * B);
                    float R2  = -2.0f * RP;
                    U[k] = __builtin_fmaf(B, R2, 1.0f);
                    V[k] = __builtin_fmaf(A, R2, 1.0f);
                    Z[k] = __builtin_fmaf((B - A) * RP, d2[k], wv[k]);
                }
            }
            if (rep == 0) {
                if (v0) out[e0 + s_idx[wid][r0]] = Z[0];
                if (v1) out[e0 + s_idx[wid][r1]] = Z[1];
            } else if (cnt & 0x40000000u) {   // never true; unprovable (ballot-derived)
                if (v0) out[e0 + s_idx[wid][r0]] = Z[0];
                if (v1) out[e0 + s_idx[wid][r1]] = Z[1];
            }
        }
    }
}

extern "C" void kernel_launch(void* const* d_in, const int* in_sizes, int n_in,
                              void* d_out, int out_size, void* d_ws, size_t ws_size,
                              hipStream_t stream) {
    const float* x = (const float*)d_in[0];
    float* out = (float*)d_out;
    long long n = in_sizes[0];
    long long waves  = (n + WAVE_ELEMS - 1) / WAVE_ELEMS;
    long long blocks = (waves + WAVES_PER_BLOCK - 1) / WAVES_PER_BLOCK;
    lee_wave<<<(int)blocks, 64 * WAVES_PER_BLOCK, 0, stream>>>(x, out, n);
}